// Round 3
// baseline (342.195 us; speedup 1.0000x reference)
//
#include <hip/hip_runtime.h>

// Fused: 2x nearest-upsample + replication-pad(1) + depthwise 3x3 conv + bias.
// Collapses to a parity-dependent 2x2 blend of the ORIGINAL input:
//   even out-coord: src (i-1, i) with weights (wrow0, wrow1+wrow2) (resp. cols)
//   odd  out-coord: src (i, i+1) with weights (wrow0+wrow1, wrow2)
// Edge clamp reproduces the replication pad exactly.

constexpr int BB = 8, CC = 128, HH = 128, WW = 128;
constexpr int W2 = WW / 2;      // 64 col-pairs per row; one wave == one row
constexpr int WO = 2 * WW;      // 256
constexpr int HO = 2 * HH;      // 256

typedef float v4f __attribute__((ext_vector_type(4)));  // clang vector: OK for nontemporal builtin
typedef float v2f __attribute__((ext_vector_type(2)));

// hsum: horizontal blend of one source row (L, X, Y, R = cols c0-1, c0, c0+1, c0+2)
// with 3-tap weights (u0,u1,u2), producing output columns 4cp..4cp+3.
__device__ __forceinline__ void hsum(float u0, float u1, float u2,
                                     float L, float X, float Y, float R,
                                     v4f& acc) {
    float u12 = u1 + u2;
    float u01 = u0 + u1;
    acc.x += u0 * L + u12 * X;   // even col: (cl, c0)
    acc.y += u01 * X + u2 * Y;   // odd  col: (c0, c1)
    acc.z += u0 * X + u12 * Y;   // even col: (c0, c1)
    acc.w += u01 * Y + u2 * R;   // odd  col: (c1, cr)
}

__global__ __launch_bounds__(256) void upblur_kernel(
    const float* __restrict__ x, const float* __restrict__ wts,
    const float* __restrict__ bias, float* __restrict__ out)
{
    const int t = blockIdx.x * blockDim.x + threadIdx.x;   // 0 .. CC*HH*W2-1 (2^21)
    const int cp = t & (W2 - 1);              // col-pair 0..63
    const int r  = (t >> 6) & (HH - 1);       // row 0..127
    const int ch = t >> 13;                   // channel 0..127

    // per-channel 3x3 weights + bias: loaded ONCE, reused for all batches
    const float* wp = wts + ch * 9;
    const float w00 = wp[0], w01 = wp[1], w02 = wp[2];
    const float w10 = wp[3], w11 = wp[4], w12 = wp[5];
    const float w20 = wp[6], w21 = wp[7], w22 = wp[8];
    const float bv = bias[ch];
    // pre-fold vertical weight pairs
    const float e0 = w00,        e1 = w01,        e2 = w02;        // even row, src rm
    const float f0 = w10 + w20,  f1 = w11 + w21,  f2 = w12 + w22;  // even row, src r
    const float g0 = w00 + w10,  g1 = w01 + w11,  g2 = w02 + w12;  // odd row,  src r
    const float h0 = w20,        h1 = w21,        h2 = w22;        // odd row,  src rp

    const int rm = (r > 0) ? r - 1 : 0;
    const int rp = (r < HH - 1) ? r + 1 : HH - 1;
    const int c0 = 2 * cp;
    const int cl = (c0 > 0) ? c0 - 1 : 0;
    const int cr = (c0 + 2 < WW) ? c0 + 2 : WW - 1;

    #pragma unroll
    for (int b = 0; b < BB; ++b) {
        const float* xp = x + ((long long)(b * CC + ch) * HH) * WW;
        const float* row_m = xp + rm * WW;
        const float* row_0 = xp + r  * WW;
        const float* row_p = xp + rp * WW;
        const v2f vm = *reinterpret_cast<const v2f*>(row_m + c0);
        const float Lm = row_m[cl], Rm = row_m[cr];
        const v2f v0 = *reinterpret_cast<const v2f*>(row_0 + c0);
        const float L0 = row_0[cl], R0 = row_0[cr];
        const v2f vp = *reinterpret_cast<const v2f*>(row_p + c0);
        const float Lp = row_p[cl], Rp = row_p[cr];

        v4f oE = {bv, bv, bv, bv};   // output row 2r
        hsum(e0, e1, e2, Lm, vm.x, vm.y, Rm, oE);
        hsum(f0, f1, f2, L0, v0.x, v0.y, R0, oE);

        v4f oO = {bv, bv, bv, bv};   // output row 2r+1
        hsum(g0, g1, g2, L0, v0.x, v0.y, R0, oO);
        hsum(h0, h1, h2, Lp, vp.x, vp.y, Rp, oO);

        float* op = out + ((long long)(b * CC + ch) * HO + 2 * r) * WO + 4 * cp;
        __builtin_nontemporal_store(oE, reinterpret_cast<v4f*>(op));
        __builtin_nontemporal_store(oO, reinterpret_cast<v4f*>(op + WO));
    }
}

extern "C" void kernel_launch(void* const* d_in, const int* in_sizes, int n_in,
                              void* d_out, int out_size, void* d_ws, size_t ws_size,
                              hipStream_t stream) {
    const float* x    = (const float*)d_in[0];
    const float* wts  = (const float*)d_in[1];
    const float* bias = (const float*)d_in[2];
    float* out = (float*)d_out;

    const int block = 256;
    const int grid = (CC * HH * W2) / block;   // 8192 blocks, one (ch,r,cp) per thread
    upblur_kernel<<<grid, block, 0, stream>>>(x, wts, bias, out);
}

// Round 4
// 308.680 us; speedup vs baseline: 1.1086x; 1.1086x over previous
//
#include <hip/hip_runtime.h>

// Fused: 2x nearest-upsample + replication-pad(1) + depthwise 3x3 conv + bias.
// Collapses to a parity-dependent 2x2 blend of the ORIGINAL input.
//   even out-coord 2i:   src (i-1, i) weights (t0, t1+t2)
//   odd  out-coord 2i+1: src (i, i+1) weights (t0+t1, t2)
// Row-pair tile: thread owns input rows (2tr, 2tr+1) x input cols (2cp, 2cp+1)
//   -> 4x4 output block, 4 contiguous nontemporal float4 stores.
// Horizontal neighbors come from adjacent LANES (wave == full input row), so
// the only loads are 4x 8B row loads; wave-edge lanes coincide with the
// replication clamp (lane0: L=own.x, lane63: R=own.y).

constexpr int BB = 8, CC = 128, HH = 128, WW = 128;
constexpr int W2 = WW / 2;      // 64 col-pairs; one wave == one input row
constexpr int H2 = HH / 2;      // 64 row-pairs
constexpr int WO = 2 * WW;      // 256
constexpr int HO = 2 * HH;      // 256

typedef float v4f __attribute__((ext_vector_type(4)));
typedef float v2f __attribute__((ext_vector_type(2)));

// acc += horizontal 3-tap blend (u0,u1,u2) of one source row (L,X,Y,R)
__device__ __forceinline__ void hsum(float u0, float u1, float u2,
                                     float L, float X, float Y, float R,
                                     v4f& acc) {
    float u12 = u1 + u2;
    float u01 = u0 + u1;
    acc.x += u0 * L + u12 * X;   // out col 4cp   (even): (cl, c0)
    acc.y += u01 * X + u2 * Y;   // out col 4cp+1 (odd):  (c0, c1)
    acc.z += u0 * X + u12 * Y;   // out col 4cp+2 (even): (c0, c1)
    acc.w += u01 * Y + u2 * R;   // out col 4cp+3 (odd):  (c1, cr)
}

// L/R neighbors of this lane's col-pair via cross-lane shuffle + edge clamp
__device__ __forceinline__ void neighbors(v2f v, int lane, float& L, float& R) {
    L = __shfl_up(v.y, 1);
    R = __shfl_down(v.x, 1);
    if (lane == 0)  L = v.x;     // col clamp at 0  (== replication pad)
    if (lane == 63) R = v.y;     // col clamp at W-1
}

__global__ __launch_bounds__(256) void upblur_kernel(
    const float* __restrict__ x, const float* __restrict__ wts,
    const float* __restrict__ bias, float* __restrict__ out)
{
    const int t  = blockIdx.x * blockDim.x + threadIdx.x;  // 0 .. 2^22-1
    const int cp = t & (W2 - 1);           // col-pair 0..63 == lane id
    const int tr = (t >> 6) & (H2 - 1);    // row-pair 0..63
    const int ch = (t >> 12) & (CC - 1);   // channel (block-uniform)
    const int b  = t >> 19;                // batch

    // weights/bias are wave-uniform -> force SGPR so they become s_loads
    const int chu = __builtin_amdgcn_readfirstlane(ch);
    const float* wp = wts + chu * 9;
    const float w00 = wp[0], w01 = wp[1], w02 = wp[2];
    const float w10 = wp[3], w11 = wp[4], w12 = wp[5];
    const float w20 = wp[6], w21 = wp[7], w22 = wp[8];
    const float bv = bias[chu];
    // folded weight triples (shared by all 4 output rows)
    const float e0 = w00,       e1 = w01,       e2 = w02;        // even row, upper src
    const float f0 = w10 + w20, f1 = w11 + w21, f2 = w12 + w22;  // even row, lower src
    const float g0 = w00 + w10, g1 = w01 + w11, g2 = w02 + w12;  // odd row, upper src
    const float h0 = w20,       h1 = w21,       h2 = w22;        // odd row, lower src

    const int r0 = 2 * tr;
    const int r1 = r0 + 1;
    const int rm = (r0 > 0) ? r0 - 1 : 0;
    const int rp = (r1 < HH - 1) ? r1 + 1 : HH - 1;
    const int c0 = 2 * cp;

    const float* xp = x + ((long long)(b * CC + ch) * HH) * WW + c0;
    const v2f vm = *reinterpret_cast<const v2f*>(xp + rm * WW);
    const v2f v0 = *reinterpret_cast<const v2f*>(xp + r0 * WW);
    const v2f v1 = *reinterpret_cast<const v2f*>(xp + r1 * WW);
    const v2f vp = *reinterpret_cast<const v2f*>(xp + rp * WW);

    float Lm, Rm, L0, R0, L1, R1, Lp, Rp;
    neighbors(vm, cp, Lm, Rm);
    neighbors(v0, cp, L0, R0);
    neighbors(v1, cp, L1, R1);
    neighbors(vp, cp, Lp, Rp);

    v4f oA = {bv, bv, bv, bv};   // out row 4tr   (even of r0): e@rm + f@r0
    hsum(e0, e1, e2, Lm, vm.x, vm.y, Rm, oA);
    hsum(f0, f1, f2, L0, v0.x, v0.y, R0, oA);

    v4f oB = {bv, bv, bv, bv};   // out row 4tr+1 (odd of r0): g@r0 + h@r1
    hsum(g0, g1, g2, L0, v0.x, v0.y, R0, oB);
    hsum(h0, h1, h2, L1, v1.x, v1.y, R1, oB);

    v4f oC = {bv, bv, bv, bv};   // out row 4tr+2 (even of r1): e@r0 + f@r1
    hsum(e0, e1, e2, L0, v0.x, v0.y, R0, oC);
    hsum(f0, f1, f2, L1, v1.x, v1.y, R1, oC);

    v4f oD = {bv, bv, bv, bv};   // out row 4tr+3 (odd of r1): g@r1 + h@rp
    hsum(g0, g1, g2, L1, v1.x, v1.y, R1, oD);
    hsum(h0, h1, h2, Lp, vp.x, vp.y, Rp, oD);

    float* op = out + ((long long)(b * CC + ch) * HO + 4 * tr) * WO + 4 * cp;
    __builtin_nontemporal_store(oA, reinterpret_cast<v4f*>(op));
    __builtin_nontemporal_store(oB, reinterpret_cast<v4f*>(op + WO));
    __builtin_nontemporal_store(oC, reinterpret_cast<v4f*>(op + 2 * WO));
    __builtin_nontemporal_store(oD, reinterpret_cast<v4f*>(op + 3 * WO));
}

extern "C" void kernel_launch(void* const* d_in, const int* in_sizes, int n_in,
                              void* d_out, int out_size, void* d_ws, size_t ws_size,
                              hipStream_t stream) {
    const float* x    = (const float*)d_in[0];
    const float* wts  = (const float*)d_in[1];
    const float* bias = (const float*)d_in[2];
    float* out = (float*)d_out;

    const int block = 256;
    const int grid = (BB * CC * H2 * W2) / block;   // 16384 blocks, 1 tile/thread
    upblur_kernel<<<grid, block, 0, stream>>>(x, wts, bias, out);
}